// Round 1
// baseline (247.449 us; speedup 1.0000x reference)
//
#include <hip/hip_runtime.h>
#include <stdint.h>

typedef __attribute__((ext_vector_type(8))) short short8v;
typedef __attribute__((ext_vector_type(4))) float f32x4;

// ---- LDS byte offsets (all 16B-aligned) ----
#define XST_OFF 0         // [128 l][136 c] bf16, row stride 272B
#define P_OFF   34816     // [128 i][136 j] bf16
#define QT_OFF  69632     // [128 i][40 d] bf16, row stride 80B
#define KT_OFF  79872     // [128 j][40 d]
#define OT_OFF  90112     // [128 i][40 d]
#define WP_OFF  100352    // [128 o][40 d]
#define VH_OFF  110592    // [32 d][136 j], row stride 272B
#define WS_OFF  119296    // [96 r][136 c], row stride 272B
#define SMEM_BYTES 145408

__device__ __forceinline__ unsigned short f2bf(float f) {
    unsigned int b = __float_as_uint(f);
    b += 0x7FFFu + ((b >> 16) & 1u);
    return (unsigned short)(b >> 16);
}
__device__ __forceinline__ unsigned int pack2(float a, float b) {
    return (unsigned int)f2bf(a) | ((unsigned int)f2bf(b) << 16);
}
__device__ __forceinline__ float bf2f(unsigned short u) {
    return __uint_as_float(((unsigned int)u) << 16);
}
__device__ __forceinline__ unsigned short loadbf(const float* p) { return f2bf(*p); }
__device__ __forceinline__ unsigned short loadbf(const unsigned short* p) { return *p; }

// DMODE: 0 = write 0.5*Y to fp32 out at [b][o][row][l]
//        1 = write 0.5*Y to bf16 W2 at [b][o][row][l]
//        2 = accumulate 0.5*Y into fp32 out at [b][o][l][row] (width fallback)
template<typename SrcT, int DMODE>
__global__ __launch_bounds__(512, 2)
void attn_kernel(const SrcT* __restrict__ src,
                 const float* __restrict__ wqkv,
                 const float* __restrict__ wproj,
                 const float* __restrict__ bias,
                 void* __restrict__ dstv,
                 int rs, int ls)
{
    extern __shared__ char smem[];
    const int t    = threadIdx.x;
    const int lane = t & 63;
    const int wv   = t >> 6;      // wave 0..7
    const int cc   = lane & 15;   // frag col / A-row lane index
    const int qq   = lane >> 4;   // lane quarter
    const int b    = blockIdx.x >> 7;
    const int row  = blockIdx.x & 127;

    // ---- phase 0: gather X^T (bf16) into XST: XsT[l][c] ----
    {
        const int sbase = b * (128 * 128 * 128);
        #pragma unroll
        for (int it = 0; it < 4; ++it) {
            int task = t + 512 * it;          // 2048 granules (l, c8)
            int l  = task & 127;
            int c8 = task >> 7;               // 0..15
            const SrcT* p = src + sbase + (c8 * 8) * 16384 + row * rs + l * ls;
            unsigned int u0 = (unsigned int)loadbf(p)             | ((unsigned int)loadbf(p + 16384)   << 16);
            unsigned int u1 = (unsigned int)loadbf(p + 2 * 16384) | ((unsigned int)loadbf(p + 3 * 16384) << 16);
            unsigned int u2 = (unsigned int)loadbf(p + 4 * 16384) | ((unsigned int)loadbf(p + 5 * 16384) << 16);
            unsigned int u3 = (unsigned int)loadbf(p + 6 * 16384) | ((unsigned int)loadbf(p + 7 * 16384) << 16);
            *(uint4*)(smem + XST_OFF + l * 272 + c8 * 16) = make_uint4(u0, u1, u2, u3);
        }
    }

    float biasr[4];
    #pragma unroll
    for (int r = 0; r < 4; ++r) biasr[r] = bias[wv * 16 + 4 * qq + r];

    f32x4 yacc[8];
    #pragma unroll
    for (int i = 0; i < 8; ++i) yacc[i] = (f32x4){0.f, 0.f, 0.f, 0.f};

    const float QSC = 0.17677669529663687f;  // 1/sqrt(32)
    const f32x4 zf4 = (f32x4){0.f, 0.f, 0.f, 0.f};

    for (int h = 0; h < 4; ++h) {
        // ---- stage W_h: rows {q,k,v} x 32 for this head, bf16 [96][136] ----
        #pragma unroll
        for (int it = 0; it < 3; ++it) {
            int task = t + 512 * it;          // < 1536
            int r96 = task >> 4;              // 0..95
            int c8  = task & 15;
            int g   = r96 >> 5;               // 0:q 1:k 2:v
            int rl  = r96 & 31;
            const float* wp = wqkv + (g * 128 + h * 32 + rl) * 128 + c8 * 8;
            float4 va = *(const float4*)wp;
            float4 vb = *(const float4*)(wp + 4);
            *(uint4*)(smem + WS_OFF + r96 * 272 + c8 * 16) =
                make_uint4(pack2(va.x, va.y), pack2(va.z, va.w),
                           pack2(vb.x, vb.y), pack2(vb.z, vb.w));
        }
        __syncthreads();  // B1: W_h (and on h=0, XsT) visible

        // ---- QKV GEMM: [96 x 128] = Wstage * XsT^T ----
        {
            const int og = wv & 1;            // o-group: 3 o-tiles each
            const int lg = wv >> 1;           // l-group: 2 l-tiles each
            f32x4 acc[3][2];
            #pragma unroll
            for (int ot = 0; ot < 3; ++ot)
                #pragma unroll
                for (int lt = 0; lt < 2; ++lt) acc[ot][lt] = zf4;
            #pragma unroll
            for (int kk = 0; kk < 4; ++kk) {
                short8v A[3], Bf[2];
                #pragma unroll
                for (int ot = 0; ot < 3; ++ot)
                    A[ot] = *(const short8v*)(smem + WS_OFF + (og * 48 + ot * 16 + cc) * 272 + kk * 64 + qq * 16);
                #pragma unroll
                for (int lt = 0; lt < 2; ++lt)
                    Bf[lt] = *(const short8v*)(smem + XST_OFF + (lg * 32 + lt * 16 + cc) * 272 + kk * 64 + qq * 16);
                #pragma unroll
                for (int ot = 0; ot < 3; ++ot)
                    #pragma unroll
                    for (int lt = 0; lt < 2; ++lt)
                        acc[ot][lt] = __builtin_amdgcn_mfma_f32_16x16x32_bf16(A[ot], Bf[lt], acc[ot][lt], 0, 0, 0);
            }
            // write outputs: got 0,1 -> QT (scaled, transposed); 2,3 -> KT; 4,5 -> V natural
            #pragma unroll
            for (int ot = 0; ot < 3; ++ot) {
                int got = og * 3 + ot;
                #pragma unroll
                for (int lt = 0; lt < 2; ++lt) {
                    int l0 = (lg * 2 + lt) * 16 + cc;
                    f32x4 v = acc[ot][lt];
                    if (got < 2) {
                        int d0 = got * 16 + 4 * qq;
                        *(uint2*)(smem + QT_OFF + l0 * 80 + d0 * 2) =
                            make_uint2(pack2(v[0] * QSC, v[1] * QSC), pack2(v[2] * QSC, v[3] * QSC));
                    } else if (got < 4) {
                        int d0 = (got - 2) * 16 + 4 * qq;
                        *(uint2*)(smem + KT_OFF + l0 * 80 + d0 * 2) =
                            make_uint2(pack2(v[0], v[1]), pack2(v[2], v[3]));
                    } else {
                        int d0 = (got - 4) * 16 + 4 * qq;
                        #pragma unroll
                        for (int r = 0; r < 4; ++r)
                            *(unsigned short*)(smem + VH_OFF + (d0 + r) * 272 + l0 * 2) = f2bf(v[r]);
                    }
                }
            }
        }
        // ---- stage Wproj head-slice [128 o][32 d] (overlaps with QKV, post-B1) ----
        {
            int o = t >> 2, d8 = t & 3;
            const float* wp = wproj + o * 128 + h * 32 + d8 * 8;
            float4 va = *(const float4*)wp;
            float4 vb = *(const float4*)(wp + 4);
            *(uint4*)(smem + WP_OFF + o * 80 + d8 * 16) =
                make_uint4(pack2(va.x, va.y), pack2(va.z, va.w),
                           pack2(vb.x, vb.y), pack2(vb.z, vb.w));
        }
        __syncthreads();  // B2: QT/KT/V/WpS visible

        // ---- S = Q^T K (wave wv owns i-tile wv), then softmax ----
        f32x4 sacc[8];
        {
            short8v aq = *(const short8v*)(smem + QT_OFF + (wv * 16 + cc) * 80 + qq * 16);
            #pragma unroll
            for (int jt = 0; jt < 8; ++jt) {
                short8v bk = *(const short8v*)(smem + KT_OFF + (jt * 16 + cc) * 80 + qq * 16);
                sacc[jt] = __builtin_amdgcn_mfma_f32_16x16x32_bf16(aq, bk, zf4, 0, 0, 0);
            }
        }
        float mx[4] = {-3.4e38f, -3.4e38f, -3.4e38f, -3.4e38f};
        #pragma unroll
        for (int jt = 0; jt < 8; ++jt)
            #pragma unroll
            for (int r = 0; r < 4; ++r) mx[r] = fmaxf(mx[r], sacc[jt][r]);
        #pragma unroll
        for (int off = 1; off < 16; off <<= 1)
            #pragma unroll
            for (int r = 0; r < 4; ++r) mx[r] = fmaxf(mx[r], __shfl_xor(mx[r], off));
        float sm[4] = {0.f, 0.f, 0.f, 0.f};
        #pragma unroll
        for (int jt = 0; jt < 8; ++jt)
            #pragma unroll
            for (int r = 0; r < 4; ++r) {
                float p = exp2f((sacc[jt][r] - mx[r]) * 1.4426950408889634f);
                sacc[jt][r] = p;
                sm[r] += p;
            }
        #pragma unroll
        for (int off = 1; off < 16; off <<= 1)
            #pragma unroll
            for (int r = 0; r < 4; ++r) sm[r] += __shfl_xor(sm[r], off);
        float rden[4];
        #pragma unroll
        for (int r = 0; r < 4; ++r) rden[r] = 1.0f / sm[r];
        // write P (unnormalized) to LDS [i][j]
        #pragma unroll
        for (int jt = 0; jt < 8; ++jt)
            #pragma unroll
            for (int r = 0; r < 4; ++r)
                *(unsigned short*)(smem + P_OFF + (wv * 16 + 4 * qq + r) * 272 + (jt * 16 + cc) * 2) = f2bf(sacc[jt][r]);
        __syncthreads();  // B3: P visible

        // ---- PV: out^T[i][d] (wave wv -> i-tile wv, 2 d-tiles) ----
        {
            f32x4 oacc[2] = {zf4, zf4};
            #pragma unroll
            for (int kt = 0; kt < 4; ++kt) {
                short8v pa = *(const short8v*)(smem + P_OFF + (wv * 16 + cc) * 272 + kt * 64 + qq * 16);
                #pragma unroll
                for (int dt = 0; dt < 2; ++dt) {
                    short8v vb = *(const short8v*)(smem + VH_OFF + (dt * 16 + cc) * 272 + kt * 64 + qq * 16);
                    oacc[dt] = __builtin_amdgcn_mfma_f32_16x16x32_bf16(pa, vb, oacc[dt], 0, 0, 0);
                }
            }
            #pragma unroll
            for (int dt = 0; dt < 2; ++dt)
                #pragma unroll
                for (int r = 0; r < 4; ++r) {
                    float v = oacc[dt][r] * rden[r];
                    *(unsigned short*)(smem + OT_OFF + (wv * 16 + 4 * qq + r) * 80 + (dt * 16 + cc) * 2) = f2bf(v);
                }
        }
        __syncthreads();  // B4: OT visible

        // ---- proj accumulate: Y[o][i] += WpS[o][:] * OT[i][:] (wave wv -> o-tile wv) ----
        {
            short8v aw = *(const short8v*)(smem + WP_OFF + (wv * 16 + cc) * 80 + qq * 16);
            #pragma unroll
            for (int it = 0; it < 8; ++it) {
                short8v vb = *(const short8v*)(smem + OT_OFF + (it * 16 + cc) * 80 + qq * 16);
                yacc[it] = __builtin_amdgcn_mfma_f32_16x16x32_bf16(aw, vb, yacc[it], 0, 0, 0);
            }
        }
    }

    // ---- epilogue ----
    #pragma unroll
    for (int it = 0; it < 8; ++it) {
        #pragma unroll
        for (int r = 0; r < 4; ++r) {
            float y = (yacc[it][r] + biasr[r]) * 0.5f;
            int o = wv * 16 + 4 * qq + r;
            int l = it * 16 + cc;
            if constexpr (DMODE == 0) {
                ((float*)dstv)[((b * 128 + o) * 128 + row) * 128 + l] = y;
            } else if constexpr (DMODE == 1) {
                ((unsigned short*)dstv)[((b * 128 + o) * 128 + row) * 128 + l] = f2bf(y);
            } else {
                int idx = ((b * 128 + o) * 128 + l) * 128 + row;
                ((float*)dstv)[idx] = ((float*)dstv)[idx] + y;
            }
        }
    }
}

// x[b][c][h][w] f32 -> xT[b][c][w][h] bf16
__global__ __launch_bounds__(256)
void transpose_kernel(const float* __restrict__ x, unsigned short* __restrict__ xT)
{
    __shared__ float Ts[64][129];
    const int bc = blockIdx.x;
    const float* xin = x + bc * 16384;
    unsigned short* xo = xT + bc * 16384;
    for (int half = 0; half < 2; ++half) {
        for (int idx = threadIdx.x; idx < 8192; idx += 256) {
            int hh = idx >> 6;
            int wl = idx & 63;
            Ts[wl][hh] = xin[hh * 128 + half * 64 + wl];
        }
        __syncthreads();
        for (int idx = threadIdx.x; idx < 8192; idx += 256) {
            int wl = idx >> 7;
            int hh = idx & 127;
            xo[(half * 64 + wl) * 128 + hh] = f2bf(Ts[wl][hh]);
        }
        __syncthreads();
    }
}

// out[b][o][h][w] += W2[b][o][w][h] (W2 already holds 0.5*Yw)
__global__ __launch_bounds__(256)
void merge_kernel(const unsigned short* __restrict__ W2, float* __restrict__ out)
{
    __shared__ float Ts[64][129];
    const int bo = blockIdx.x;
    const unsigned short* win = W2 + bo * 16384;
    float* op = out + bo * 16384;
    for (int half = 0; half < 2; ++half) {
        for (int idx = threadIdx.x; idx < 8192; idx += 256) {
            int wl = idx >> 7;
            int hh = idx & 127;
            Ts[wl][hh] = bf2f(win[(half * 64 + wl) * 128 + hh]);
        }
        __syncthreads();
        for (int idx = threadIdx.x; idx < 8192; idx += 256) {
            int hh = idx >> 6;
            int wl = idx & 63;
            op[hh * 128 + half * 64 + wl] += Ts[wl][hh];
        }
        __syncthreads();
    }
}

extern "C" void kernel_launch(void* const* d_in, const int* in_sizes, int n_in,
                              void* d_out, int out_size, void* d_ws, size_t ws_size,
                              hipStream_t stream)
{
    const float* x       = (const float*)d_in[0];
    const float* wqkv_h  = (const float*)d_in[1];
    const float* wproj_h = (const float*)d_in[2];
    const float* bproj_h = (const float*)d_in[3];
    const float* wqkv_w  = (const float*)d_in[4];
    const float* wproj_w = (const float*)d_in[5];
    const float* bproj_w = (const float*)d_in[6];
    float* out = (float*)d_out;

    (void)hipFuncSetAttribute((const void*)attn_kernel<float, 0>,
                              hipFuncAttributeMaxDynamicSharedMemorySize, SMEM_BYTES);
    (void)hipFuncSetAttribute((const void*)attn_kernel<unsigned short, 1>,
                              hipFuncAttributeMaxDynamicSharedMemorySize, SMEM_BYTES);
    (void)hipFuncSetAttribute((const void*)attn_kernel<float, 2>,
                              hipFuncAttributeMaxDynamicSharedMemorySize, SMEM_BYTES);

    const bool fast = ws_size >= 67108864ull;  // xT (33.5MB bf16) + W2 (33.5MB bf16)

    // height pass: one block per (b, h); writes out = 0.5*Yh (coalesced)
    attn_kernel<float, 0><<<dim3(1024), dim3(512), SMEM_BYTES, stream>>>(
        x, wqkv_h, wproj_h, bproj_h, (void*)out, 128, 1);

    if (fast) {
        unsigned short* xT = (unsigned short*)d_ws;
        unsigned short* W2 = xT + 16777216;
        transpose_kernel<<<dim3(1024), dim3(256), 0, stream>>>(x, xT);
        attn_kernel<unsigned short, 1><<<dim3(1024), dim3(512), SMEM_BYTES, stream>>>(
            xT, wqkv_w, wproj_w, bproj_w, (void*)W2, 128, 1);
        merge_kernel<<<dim3(1024), dim3(256), 0, stream>>>(W2, out);
    } else {
        // fallback: strided gather from x, uncoalesced RMW into out
        attn_kernel<float, 2><<<dim3(1024), dim3(512), SMEM_BYTES, stream>>>(
            x, wqkv_w, wproj_w, bproj_w, (void*)out, 1, 128);
    }
}

// Round 3
// 182.150 us; speedup vs baseline: 1.3585x; 1.3585x over previous
//
#include <hip/hip_runtime.h>
#include <hip/hip_bf16.h>
#include <stdint.h>

typedef __attribute__((ext_vector_type(8))) short short8v;
typedef __attribute__((ext_vector_type(4))) float f32x4;
typedef unsigned short u16;
typedef unsigned int u32;

// ---------------- static device scratch (referenced ONLY from device code) ----------------
__device__ __align__(16) u16 g_xTw[8u * 128u * 128u * 128u];   // [b][w][h][c-swz] bf16
__device__ __align__(16) u16 g_W2[8u * 128u * 128u * 128u];    // [b][o][w][h] bf16 (0.5*Yw)
__device__ __align__(16) u16 g_wqkvP[2u * 49152u];             // [pass][h][got6][kk4][lane64][8] frag-order
__device__ __align__(16) u16 g_wpP[2u * 16384u];               // [pass][h][tile8][lane64][8] frag-order

// ---- LDS byte offsets (attn kernel) ----
#define XST_OFF 0         // [128 l][256B] bf16, 16B-chunks XOR-swizzled by (l&7)<<4
#define QT_OFF  32768     // [128 i][80B] bf16 (d 0..31 + pad)
#define KT_OFF  43008     // [128 j][80B]
#define VH_OFF  53248     // [32 d][272B] (j*2 bytes)
#define OT_OFF  61952     // [128 i][80B]
#define SMEM_BYTES 72192

__device__ __forceinline__ u16 f2bf(float f) {
    u32 b = __float_as_uint(f);
    b += 0x7FFFu + ((b >> 16) & 1u);
    return (u16)(b >> 16);
}
__device__ __forceinline__ u32 pk2(float a, float b) {
    __hip_bfloat162 h = __float22bfloat162_rn(make_float2(a, b));
    union { __hip_bfloat162 h; u32 u; } cv; cv.h = h; return cv.u;
}
__device__ __forceinline__ float bf2f(u16 u) {
    return __uint_as_float(((u32)u) << 16);
}

// ---------------- weight pre-pack: f32 -> bf16 fragment order ----------------
__global__ __launch_bounds__(512)
void prep_weights(const float* __restrict__ wqkv_h, const float* __restrict__ wproj_h,
                  const float* __restrict__ wqkv_w, const float* __restrict__ wproj_w)
{
    const float QSC = 0.17677669529663687f;   // 1/sqrt(32)
    int id = blockIdx.x * 512 + threadIdx.x;  // 16384 total chunks
    if (id < 12288) {                          // qkv chunks
        int p = id / 6144, i2 = id % 6144;
        int h = i2 / 1536, i3 = i2 % 1536;
        int t = i3 / 256,  i4 = i3 % 256;
        int kk = i4 / 64,  lane = i4 % 64;
        int cc = lane & 15, qq = lane >> 4;
        int r96 = t * 16 + cc;
        int g = r96 >> 5, rl = r96 & 31;
        const float* src = (p == 0 ? wqkv_h : wqkv_w) + (g * 128 + h * 32 + rl) * 128 + kk * 32 + qq * 8;
        float4 a = *(const float4*)src;
        float4 c = *(const float4*)(src + 4);
        float s = (g == 0) ? QSC : 1.0f;
        *(uint4*)(g_wqkvP + (size_t)id * 8) =
            make_uint4(pk2(a.x * s, a.y * s), pk2(a.z * s, a.w * s),
                       pk2(c.x * s, c.y * s), pk2(c.z * s, c.w * s));
    } else {                                   // wproj chunks
        int id2 = id - 12288;                  // [0,4096)
        int p = id2 / 2048, i2 = id2 % 2048;
        int h = i2 / 512,  i3 = i2 % 512;
        int t = i3 / 64,   lane = i3 % 64;
        int cc = lane & 15, qq = lane >> 4;
        int o = t * 16 + cc;
        const float* src = (p == 0 ? wproj_h : wproj_w) + o * 128 + h * 32 + qq * 8;
        float4 a = *(const float4*)src;
        float4 c = *(const float4*)(src + 4);
        *(uint4*)(g_wpP + (size_t)id2 * 8) =
            make_uint4(pk2(a.x, a.y), pk2(a.z, a.w), pk2(c.x, c.y), pk2(c.z, c.w));
    }
}

// ---------------- x [b][c][h][w] f32 -> g_xTw [b][w][h][c-swz] bf16 ----------------
__global__ __launch_bounds__(256)
void transpose_x(const float* __restrict__ x)
{
    __shared__ char tsm[32768];                // [128 w][256B], 16B chunks swz by (w&7)<<4
    const int b = blockIdx.x >> 6;
    const int hp = blockIdx.x & 63;
    const int tid = threadIdx.x;
    for (int hh = 0; hh < 2; ++hh) {
        const int h = hp * 2 + hh;
        #pragma unroll
        for (int it = 0; it < 16; ++it) {
            int task = it * 256 + tid;
            int w = task & 127, c4 = task >> 7;  // c4 in 0..31
            const float* p = x + (size_t)b * 2097152 + (c4 * 4) * 16384 + h * 128 + w;
            u32 u0 = pk2(p[0], p[16384]);
            u32 u1 = pk2(p[2 * 16384], p[3 * 16384]);
            int off = w * 256 + ((((c4 >> 1) << 4) ^ ((w & 7) << 4)) | ((c4 & 1) << 3));
            *(uint2*)(tsm + off) = make_uint2(u0, u1);
        }
        __syncthreads();
        #pragma unroll
        for (int it = 0; it < 8; ++it) {
            int i = it * 256 + tid;
            int w = i >> 4, c8 = i & 15;
            uint4 v = *(const uint4*)(tsm + w * 256 + ((c8 << 4) ^ ((w & 7) << 4)));
            size_t ds = ((size_t)(b * 128 + w) * 128 + h) * 128 + (((c8 << 4) ^ ((h & 7) << 4)) >> 1);
            *(uint4*)(g_xTw + ds) = v;
        }
        __syncthreads();
    }
}

// ---------------- fused axial attention ----------------
// GATHER=1: src = x f32, gather/transpose in-kernel (height pass)
// GATHER=0: src = g_xTw slab (device symbol, read directly)
// DMODE=0:  out[b][o][row][l] = 0.5*Y (f32)
// DMODE=1:  g_W2[b][o][row][l] = 0.5*Y (bf16)
template<int GATHER, int DMODE>
__global__ __launch_bounds__(512, 4)
void attn_kernel(const float* __restrict__ srcx, int pass,
                 const float* __restrict__ bias, float* __restrict__ out)
{
    extern __shared__ char smem[];
    const int t    = threadIdx.x;
    const int lane = t & 63;
    const int wv   = t >> 6;
    const int cc   = lane & 15;
    const int qq   = lane >> 4;
    const int b    = blockIdx.x >> 7;
    const int row  = blockIdx.x & 127;
    const f32x4 zf4 = (f32x4){0.f, 0.f, 0.f, 0.f};

    // ---- phase 0: stage XsT[l][c] bf16 swizzled ----
    if constexpr (GATHER) {
        #pragma unroll
        for (int it = 0; it < 4; ++it) {
            int task = t + 512 * it;
            int l = task & 127, c8 = task >> 7;
            const float* p = srcx + (size_t)b * 2097152 + (c8 * 8) * 16384 + row * 128 + l;
            u32 u0 = pk2(p[0], p[16384]);
            u32 u1 = pk2(p[2 * 16384], p[3 * 16384]);
            u32 u2 = pk2(p[4 * 16384], p[5 * 16384]);
            u32 u3 = pk2(p[6 * 16384], p[7 * 16384]);
            *(uint4*)(smem + XST_OFF + l * 256 + ((c8 * 16) ^ ((l & 7) << 4))) = make_uint4(u0, u1, u2, u3);
        }
    } else {
        const u16* slab = g_xTw + (size_t)(b * 128 + row) * 16384;  // device-side symbol ref
        #pragma unroll
        for (int it = 0; it < 4; ++it) {
            int idx = t + 512 * it;               // 16B chunks, layout == LDS layout
            *(uint4*)(smem + XST_OFF + idx * 16) = *(const uint4*)(slab + idx * 8);
        }
    }

    float biasr[4];
    #pragma unroll
    for (int r = 0; r < 4; ++r) biasr[r] = bias[wv * 16 + 4 * qq + r];

    f32x4 yacc[8];
    #pragma unroll
    for (int i = 0; i < 8; ++i) yacc[i] = zf4;

    __syncthreads();   // B0: XST visible

    const int og = wv & 1;     // o-half for QKV
    const int lg = wv >> 1;    // l-quarter for QKV

    for (int h = 0; h < 4; ++h) {
        const u16* wb  = g_wqkvP + (size_t)(pass * 4 + h) * 12288;
        const u16* wpb = g_wpP   + (size_t)(pass * 4 + h) * 4096 + (wv * 64 + lane) * 8;

        // ---- QKV GEMM: A-frags direct from global (L2), B from XST ----
        {
            f32x4 acc[3][2];
            #pragma unroll
            for (int ot = 0; ot < 3; ++ot)
                #pragma unroll
                for (int lt = 0; lt < 2; ++lt) acc[ot][lt] = zf4;
            #pragma unroll
            for (int kk = 0; kk < 4; ++kk) {
                short8v A[3], Bf[2];
                #pragma unroll
                for (int ot = 0; ot < 3; ++ot)
                    A[ot] = *(const short8v*)(wb + (((og * 3 + ot) * 4 + kk) * 64 + lane) * 8);
                #pragma unroll
                for (int lt = 0; lt < 2; ++lt) {
                    int l = lg * 32 + lt * 16 + cc;
                    Bf[lt] = *(const short8v*)(smem + XST_OFF + l * 256 + (((kk * 64 + qq * 16)) ^ ((l & 7) << 4)));
                }
                #pragma unroll
                for (int ot = 0; ot < 3; ++ot)
                    #pragma unroll
                    for (int lt = 0; lt < 2; ++lt)
                        acc[ot][lt] = __builtin_amdgcn_mfma_f32_16x16x32_bf16(A[ot], Bf[lt], acc[ot][lt], 0, 0, 0);
            }
            // write: got 0,1 -> QT[l][d]; 2,3 -> KT[l][d]; 4,5 -> VH[d][j=l]
            #pragma unroll
            for (int ot = 0; ot < 3; ++ot) {
                int got = og * 3 + ot;
                #pragma unroll
                for (int lt = 0; lt < 2; ++lt) {
                    int l0 = (lg * 2 + lt) * 16 + cc;
                    f32x4 v = acc[ot][lt];
                    if (got < 2) {
                        *(uint2*)(smem + QT_OFF + l0 * 80 + (got * 16 + 4 * qq) * 2) =
                            make_uint2(pk2(v[0], v[1]), pk2(v[2], v[3]));
                    } else if (got < 4) {
                        *(uint2*)(smem + KT_OFF + l0 * 80 + ((got - 2) * 16 + 4 * qq) * 2) =
                            make_uint2(pk2(v[0], v[1]), pk2(v[2], v[3]));
                    } else {
                        int d0 = (got - 4) * 16 + 4 * qq;
                        #pragma unroll
                        for (int r = 0; r < 4; ++r)
                            *(u16*)(smem + VH_OFF + (d0 + r) * 272 + l0 * 2) = f2bf(v[r]);
                    }
                }
            }
        }
        __syncthreads();   // B2: QT/KT/VH visible

        // ---- S^T = mfma(K,Q): lane (cc,qq) reg r holds S[i=wv*16+cc][j=jt*16+4qq+r] ----
        f32x4 sacc[8];
        {
            short8v aq = *(const short8v*)(smem + QT_OFF + (wv * 16 + cc) * 80 + qq * 16);
            #pragma unroll
            for (int jt = 0; jt < 8; ++jt) {
                short8v bk = *(const short8v*)(smem + KT_OFF + (jt * 16 + cc) * 80 + qq * 16);
                sacc[jt] = __builtin_amdgcn_mfma_f32_16x16x32_bf16(bk, aq, zf4, 0, 0, 0);
            }
        }
        // ---- softmax over j (per-lane 32 + 2 shfl_xor) ----
        float mx = -3.4e38f;
        #pragma unroll
        for (int jt = 0; jt < 8; ++jt)
            #pragma unroll
            for (int r = 0; r < 4; ++r) mx = fmaxf(mx, sacc[jt][r]);
        mx = fmaxf(mx, __shfl_xor(mx, 16));
        mx = fmaxf(mx, __shfl_xor(mx, 32));
        float sm = 0.f;
        #pragma unroll
        for (int jt = 0; jt < 8; ++jt)
            #pragma unroll
            for (int r = 0; r < 4; ++r) {
                float p = exp2f((sacc[jt][r] - mx) * 1.4426950408889634f);
                sacc[jt][r] = p;
                sm += p;
            }
        sm += __shfl_xor(sm, 16);
        sm += __shfl_xor(sm, 32);
        float rden = 1.0f / sm;
        u32 u[8][2];
        #pragma unroll
        for (int jt = 0; jt < 8; ++jt) {
            u[jt][0] = pk2(sacc[jt][0], sacc[jt][1]);
            u[jt][1] = pk2(sacc[jt][2], sacc[jt][3]);
        }

        // ---- PV: exchange P into B-frag form within stride-16 lane groups ----
        f32x4 oacc[2] = {zf4, zf4};
        const int base = cc + ((qq & 1) << 5);
        const bool hiT = (qq >> 1) != 0;
        #pragma unroll
        for (int kt = 0; kt < 4; ++kt) {
            int a0 = __shfl((int)u[2 * kt][0], base),      a1 = __shfl((int)u[2 * kt][1], base);
            int a2 = __shfl((int)u[2 * kt][0], base + 16), a3 = __shfl((int)u[2 * kt][1], base + 16);
            int b0 = __shfl((int)u[2 * kt + 1][0], base),      b1 = __shfl((int)u[2 * kt + 1][1], base);
            int b2 = __shfl((int)u[2 * kt + 1][0], base + 16), b3 = __shfl((int)u[2 * kt + 1][1], base + 16);
            union { uint4 u4; short8v s8; } pf;
            pf.u4 = make_uint4((u32)(hiT ? b0 : a0), (u32)(hiT ? b1 : a1),
                               (u32)(hiT ? b2 : a2), (u32)(hiT ? b3 : a3));
            #pragma unroll
            for (int dt = 0; dt < 2; ++dt) {
                short8v vf = *(const short8v*)(smem + VH_OFF + (dt * 16 + cc) * 272 + kt * 64 + qq * 16);
                oacc[dt] = __builtin_amdgcn_mfma_f32_16x16x32_bf16(vf, pf.s8, oacc[dt], 0, 0, 0);
            }
        }
        // O[d=dt*16+4qq+r][i=wv*16+cc] * rden -> OT[i][d]
        #pragma unroll
        for (int dt = 0; dt < 2; ++dt) {
            *(uint2*)(smem + OT_OFF + (wv * 16 + cc) * 80 + (dt * 16 + 4 * qq) * 2) =
                make_uint2(pk2(oacc[dt][0] * rden, oacc[dt][1] * rden),
                           pk2(oacc[dt][2] * rden, oacc[dt][3] * rden));
        }
        __syncthreads();   // B3: OT visible

        // ---- proj accumulate: Y[o][i] += Wp[o][d] * O[i][d] ----
        {
            short8v aw = *(const short8v*)wpb;
            #pragma unroll
            for (int it = 0; it < 8; ++it) {
                short8v of = *(const short8v*)(smem + OT_OFF + (it * 16 + cc) * 80 + qq * 16);
                yacc[it] = __builtin_amdgcn_mfma_f32_16x16x32_bf16(aw, of, yacc[it], 0, 0, 0);
            }
        }
    }

    // ---- epilogue: Y[o = wv*16+4qq+r][l = it*16+cc] ----
    #pragma unroll
    for (int it = 0; it < 8; ++it) {
        #pragma unroll
        for (int r = 0; r < 4; ++r) {
            float y = (yacc[it][r] + biasr[r]) * 0.5f;
            int o = wv * 16 + 4 * qq + r;
            int l = it * 16 + cc;
            size_t idx = ((size_t)(b * 128 + o) * 128 + row) * 128 + l;
            if constexpr (DMODE == 0) out[idx] = y;
            else                      g_W2[idx] = f2bf(y);
        }
    }
}

// ---------------- merge: out[b][o][h][w] += T(g_W2[b][o][w][h]) ----------------
__global__ __launch_bounds__(256)
void merge_w(float* __restrict__ out)
{
    __shared__ char msm[128 * 264];              // [128 w][264B]
    const int b = blockIdx.x >> 7;
    const int o = blockIdx.x & 127;
    const int tid = threadIdx.x;
    const u16* slab = g_W2 + (size_t)(b * 128 + o) * 16384;
    #pragma unroll
    for (int it = 0; it < 8; ++it) {
        int i = it * 256 + tid;
        int w = i >> 4, h8 = i & 15;
        *(uint4*)(msm + w * 264 + h8 * 16) = *(const uint4*)(slab + w * 128 + h8 * 8);
    }
    __syncthreads();
    float* op = out + (size_t)(b * 128 + o) * 16384;
    #pragma unroll
    for (int it = 0; it < 8; ++it) {
        int i = it * 256 + tid;
        int h = i >> 4, w8 = i & 15;
        float f[8];
        #pragma unroll
        for (int k = 0; k < 8; ++k)
            f[k] = bf2f(*(const u16*)(msm + (w8 * 8 + k) * 264 + h * 2));
        float* dp = op + h * 128 + w8 * 8;
        float4 v0 = *(float4*)dp;
        float4 v1 = *(float4*)(dp + 4);
        v0.x += f[0]; v0.y += f[1]; v0.z += f[2]; v0.w += f[3];
        v1.x += f[4]; v1.y += f[5]; v1.z += f[6]; v1.w += f[7];
        *(float4*)dp = v0;
        *(float4*)(dp + 4) = v1;
    }
}

extern "C" void kernel_launch(void* const* d_in, const int* in_sizes, int n_in,
                              void* d_out, int out_size, void* d_ws, size_t ws_size,
                              hipStream_t stream)
{
    const float* x       = (const float*)d_in[0];
    const float* wqkv_h  = (const float*)d_in[1];
    const float* wproj_h = (const float*)d_in[2];
    const float* bproj_h = (const float*)d_in[3];
    const float* wqkv_w  = (const float*)d_in[4];
    const float* wproj_w = (const float*)d_in[5];
    const float* bproj_w = (const float*)d_in[6];
    float* out = (float*)d_out;

    (void)hipFuncSetAttribute((const void*)attn_kernel<1, 0>,
                              hipFuncAttributeMaxDynamicSharedMemorySize, SMEM_BYTES);
    (void)hipFuncSetAttribute((const void*)attn_kernel<0, 1>,
                              hipFuncAttributeMaxDynamicSharedMemorySize, SMEM_BYTES);

    // 1) pack weights to bf16 fragment order (Q pre-scaled)
    prep_weights<<<dim3(32), dim3(512), 0, stream>>>(wqkv_h, wproj_h, wqkv_w, wproj_w);
    // 2) x -> channel-last bf16 slabs for the width pass
    transpose_x<<<dim3(512), dim3(256), 0, stream>>>(x);
    // 3) height pass: in-kernel gather, writes out '='
    attn_kernel<1, 0><<<dim3(1024), dim3(512), SMEM_BYTES, stream>>>(x, 0, bproj_h, out);
    // 4) width pass: slab-staged (reads g_xTw device-side), writes g_W2 bf16
    attn_kernel<0, 1><<<dim3(1024), dim3(512), SMEM_BYTES, stream>>>(nullptr, 1, bproj_w, out);
    // 5) merge: out += transpose(g_W2)
    merge_w<<<dim3(1024), dim3(256), 0, stream>>>(out);
}

// Round 5
// 170.256 us; speedup vs baseline: 1.4534x; 1.0699x over previous
//
#include <hip/hip_runtime.h>
#include <hip/hip_bf16.h>
#include <stdint.h>

typedef __attribute__((ext_vector_type(8))) short short8v;
typedef __attribute__((ext_vector_type(4))) float f32x4;
typedef unsigned short u16;
typedef unsigned int u32;

// ---------------- static device scratch (referenced ONLY from device code) ----------------
__device__ __align__(16) u16 g_xh [8u * 128u * 128u * 128u];   // [b][h][w][c-swz] bf16 (height slabs)
__device__ __align__(16) u16 g_xTw[8u * 128u * 128u * 128u];   // [b][w][h][c-swz] bf16 (width slabs)
__device__ __align__(16) u16 g_W2 [8u * 128u * 128u * 128u];   // [b][o][w][h] bf16 (0.5*Yw)
__device__ __align__(16) u16 g_wqkvP[2u * 49152u];             // [pass][h][tile6][kk4][lane64][8]
__device__ __align__(16) u16 g_wpP [2u * 16384u];              // [pass][h][tile8][lane64][8]

// ---- LDS byte offsets (attn kernel) — round-3 proven layout ----
#define XST_OFF 0         // [128 l][256B], 16B chunks XOR-swizzled by (l&7)<<4
#define QT_OFF  32768     // [128 i][80B] bf16 (d 0..31 + pad)
#define KT_OFF  43008     // [128 j][80B]
#define VH_OFF  53248     // [32 d][272B] (j*2 bytes)
#define OT_OFF  61952     // [128 i][80B]
#define SMEM_BYTES 72192

__device__ __forceinline__ u16 f2bf(float f) {
    u32 b = __float_as_uint(f);
    b += 0x7FFFu + ((b >> 16) & 1u);
    return (u16)(b >> 16);
}
__device__ __forceinline__ u32 pk2(float a, float b) {
    __hip_bfloat162 h = __float22bfloat162_rn(make_float2(a, b));
    union { __hip_bfloat162 h; u32 u; } cv; cv.h = h; return cv.u;
}
__device__ __forceinline__ float bf2f(u16 u) {
    return __uint_as_float(((u32)u) << 16);
}

// ---------------- weight pre-pack: f32 -> bf16 fragment order (round-3 proven) ----------------
__global__ __launch_bounds__(512)
void prep_weights(const float* __restrict__ wqkv_h, const float* __restrict__ wproj_h,
                  const float* __restrict__ wqkv_w, const float* __restrict__ wproj_w)
{
    const float QSC = 0.17677669529663687f;   // 1/sqrt(32)
    int id = blockIdx.x * 512 + threadIdx.x;  // 16384 chunks
    if (id < 12288) {
        int p = id / 6144, i2 = id % 6144;
        int h = i2 / 1536, i3 = i2 % 1536;
        int t = i3 / 256,  i4 = i3 % 256;     // t: 0,1=Q 2,3=K 4,5=V
        int kk = i4 / 64,  lane = i4 % 64;
        int cc = lane & 15, qq = lane >> 4;
        int r96 = t * 16 + cc;
        int g = r96 >> 5, rl = r96 & 31;
        const float* src = (p == 0 ? wqkv_h : wqkv_w) + (g * 128 + h * 32 + rl) * 128 + kk * 32 + qq * 8;
        float4 a = *(const float4*)src;
        float4 c = *(const float4*)(src + 4);
        float s = (g == 0) ? QSC : 1.0f;
        *(uint4*)(g_wqkvP + (size_t)id * 8) =
            make_uint4(pk2(a.x * s, a.y * s), pk2(a.z * s, a.w * s),
                       pk2(c.x * s, c.y * s), pk2(c.z * s, c.w * s));
    } else {
        int id2 = id - 12288;
        int p = id2 / 2048, i2 = id2 % 2048;
        int h = i2 / 512,  i3 = i2 % 512;
        int t = i3 / 64,   lane = i3 % 64;
        int cc = lane & 15, qq = lane >> 4;
        int o = t * 16 + cc;
        const float* src = (p == 0 ? wproj_h : wproj_w) + o * 128 + h * 32 + qq * 8;
        float4 a = *(const float4*)src;
        float4 c = *(const float4*)(src + 4);
        *(uint4*)(g_wpP + (size_t)id2 * 8) =
            make_uint4(pk2(a.x, a.y), pk2(a.z, a.w), pk2(c.x, c.y), pk2(c.z, c.w));
    }
}

// ---------------- x [b][c][h][w] f32 -> g_xh [b][h][w][c-swz] + g_xTw [b][w][h][c-swz] ----------------
__global__ __launch_bounds__(256)
void transpose_x(const float* __restrict__ x)
{
    __shared__ char tsm[32768];                // [128 w][256B], chunk c8 stored at (c8<<4)^((w&7)<<4)
    const int b = blockIdx.x >> 6;
    const int hp = blockIdx.x & 63;
    const int tid = threadIdx.x;
    for (int hh = 0; hh < 2; ++hh) {
        const int h = hp * 2 + hh;
        #pragma unroll
        for (int it = 0; it < 16; ++it) {
            int task = it * 256 + tid;
            int w = task & 127, c4 = task >> 7;
            const float* p = x + (size_t)b * 2097152 + (c4 * 4) * 16384 + h * 128 + w;
            u32 u0 = pk2(p[0], p[16384]);
            u32 u1 = pk2(p[2 * 16384], p[3 * 16384]);
            int off = w * 256 + ((((c4 >> 1) << 4) ^ ((w & 7) << 4)) | ((c4 & 1) << 3));
            *(uint2*)(tsm + off) = make_uint2(u0, u1);
        }
        __syncthreads();
        // drain A: g_xh slab (b,h) = tsm verbatim (linear, coalesced); layout == attn LDS layout
        #pragma unroll
        for (int it = 0; it < 8; ++it) {
            int i = it * 256 + tid;
            *(uint4*)(g_xh + (size_t)(b * 128 + h) * 16384 + i * 8) = *(const uint4*)(tsm + i * 16);
        }
        // drain B: g_xTw rows (w-slabs), re-swizzled by h (round-3 proven)
        #pragma unroll
        for (int it = 0; it < 8; ++it) {
            int i = it * 256 + tid;
            int w = i >> 4, c8 = i & 15;
            uint4 v = *(const uint4*)(tsm + w * 256 + ((c8 << 4) ^ ((w & 7) << 4)));
            size_t ds = ((size_t)(b * 128 + w) * 128 + h) * 128 + (((c8 << 4) ^ ((h & 7) << 4)) >> 1);
            *(uint4*)(g_xTw + ds) = v;
        }
        __syncthreads();
    }
}

// ---------------- fused axial attention, both passes in one dispatch ----------------
// pass = blockIdx>>10. pass0: slab g_xh, write out f32 '='. pass1: slab g_xTw, write g_W2 bf16.
// Per-head pipeline is the round-3 PROVEN body (QT/KT/VH/OT in LDS, 2 barriers/head).
__global__ __launch_bounds__(512, 4)
void attn_kernel(const float* __restrict__ bias_h, const float* __restrict__ bias_w,
                 float* __restrict__ out)
{
    extern __shared__ char smem[];
    const int t    = threadIdx.x;
    const int lane = t & 63;
    const int wv   = t >> 6;
    const int cc   = lane & 15;
    const int qq   = lane >> 4;
    const int pass = blockIdx.x >> 10;
    const int b    = (blockIdx.x >> 7) & 7;
    const int row  = blockIdx.x & 127;
    const f32x4 zf4 = (f32x4){0.f, 0.f, 0.f, 0.f};

    // ---- stage XsT[l][c] (linear slab copy; slab layout == LDS layout incl. swizzle) ----
    {
        const u16* slab = (pass ? g_xTw : g_xh) + (size_t)(b * 128 + row) * 16384;
        #pragma unroll
        for (int it = 0; it < 4; ++it) {
            int idx = t + 512 * it;
            *(uint4*)(smem + XST_OFF + idx * 16) = *(const uint4*)(slab + idx * 8);
        }
    }

    const float* bias = pass ? bias_w : bias_h;
    float biasr[4];
    #pragma unroll
    for (int r = 0; r < 4; ++r) biasr[r] = bias[wv * 16 + 4 * qq + r];

    f32x4 yacc[8];
    #pragma unroll
    for (int i = 0; i < 8; ++i) yacc[i] = zf4;

    __syncthreads();   // B0: XST visible

    const int og = wv & 1;     // o-half for QKV (3 tiles each)
    const int lg = wv >> 1;    // l-quarter for QKV (2 tiles each)

    for (int h = 0; h < 4; ++h) {
        const u16* wb  = g_wqkvP + (size_t)(pass * 4 + h) * 12288;
        const u16* wpb = g_wpP   + (size_t)(pass * 4 + h) * 4096 + (wv * 64 + lane) * 8;

        // ---- QKV GEMM: A-frags direct from global (L2), B from XST ----
        {
            f32x4 acc[3][2];
            #pragma unroll
            for (int ot = 0; ot < 3; ++ot)
                #pragma unroll
                for (int lt = 0; lt < 2; ++lt) acc[ot][lt] = zf4;
            __builtin_amdgcn_s_setprio(1);
            #pragma unroll
            for (int kk = 0; kk < 4; ++kk) {
                short8v A[3], Bf[2];
                #pragma unroll
                for (int ot = 0; ot < 3; ++ot)
                    A[ot] = *(const short8v*)(wb + (((og * 3 + ot) * 4 + kk) * 64 + lane) * 8);
                #pragma unroll
                for (int lt = 0; lt < 2; ++lt) {
                    int l = lg * 32 + lt * 16 + cc;
                    Bf[lt] = *(const short8v*)(smem + XST_OFF + l * 256 + (((kk * 64 + qq * 16)) ^ ((l & 7) << 4)));
                }
                #pragma unroll
                for (int ot = 0; ot < 3; ++ot)
                    #pragma unroll
                    for (int lt = 0; lt < 2; ++lt)
                        acc[ot][lt] = __builtin_amdgcn_mfma_f32_16x16x32_bf16(A[ot], Bf[lt], acc[ot][lt], 0, 0, 0);
            }
            __builtin_amdgcn_s_setprio(0);
            // write: got 0,1 -> QT[l][d]; 2,3 -> KT[l][d]; 4,5 -> VH[d][j=l]
            #pragma unroll
            for (int ot = 0; ot < 3; ++ot) {
                int got = og * 3 + ot;
                #pragma unroll
                for (int lt = 0; lt < 2; ++lt) {
                    int l0 = (lg * 2 + lt) * 16 + cc;
                    f32x4 v = acc[ot][lt];
                    if (got < 2) {
                        *(uint2*)(smem + QT_OFF + l0 * 80 + (got * 16 + 4 * qq) * 2) =
                            make_uint2(pk2(v[0], v[1]), pk2(v[2], v[3]));
                    } else if (got < 4) {
                        *(uint2*)(smem + KT_OFF + l0 * 80 + ((got - 2) * 16 + 4 * qq) * 2) =
                            make_uint2(pk2(v[0], v[1]), pk2(v[2], v[3]));
                    } else {
                        int d0 = (got - 4) * 16 + 4 * qq;
                        #pragma unroll
                        for (int r = 0; r < 4; ++r)
                            *(u16*)(smem + VH_OFF + (d0 + r) * 272 + l0 * 2) = f2bf(v[r]);
                    }
                }
            }
        }
        __syncthreads();   // B2: QT/KT/VH visible

        // ---- S^T = mfma(K, Q): lane (cc,qq) reg r holds S[i=wv*16+cc][j=jt*16+4qq+r] ----
        f32x4 sacc[8];
        {
            short8v aq = *(const short8v*)(smem + QT_OFF + (wv * 16 + cc) * 80 + qq * 16);
            __builtin_amdgcn_s_setprio(1);
            #pragma unroll
            for (int jt = 0; jt < 8; ++jt) {
                short8v bk = *(const short8v*)(smem + KT_OFF + (jt * 16 + cc) * 80 + qq * 16);
                sacc[jt] = __builtin_amdgcn_mfma_f32_16x16x32_bf16(bk, aq, zf4, 0, 0, 0);
            }
            __builtin_amdgcn_s_setprio(0);
        }
        // ---- softmax over j (per-lane 32 + 2 shfl_xor) ----
        float mx = -3.4e38f;
        #pragma unroll
        for (int jt = 0; jt < 8; ++jt)
            #pragma unroll
            for (int r = 0; r < 4; ++r) mx = fmaxf(mx, sacc[jt][r]);
        mx = fmaxf(mx, __shfl_xor(mx, 16));
        mx = fmaxf(mx, __shfl_xor(mx, 32));
        float sm = 0.f;
        #pragma unroll
        for (int jt = 0; jt < 8; ++jt)
            #pragma unroll
            for (int r = 0; r < 4; ++r) {
                float p = exp2f((sacc[jt][r] - mx) * 1.4426950408889634f);
                sacc[jt][r] = p;
                sm += p;
            }
        sm += __shfl_xor(sm, 16);
        sm += __shfl_xor(sm, 32);
        float rden = 1.0f / sm;
        u32 u[8][2];
        #pragma unroll
        for (int jt = 0; jt < 8; ++jt) {
            u[jt][0] = pk2(sacc[jt][0], sacc[jt][1]);
            u[jt][1] = pk2(sacc[jt][2], sacc[jt][3]);
        }

        // ---- PV: exchange P to B-frag within stride-16 lane groups (round-3 proven) ----
        f32x4 oacc[2] = {zf4, zf4};
        const int base = cc + ((qq & 1) << 5);
        const bool hiT = (qq >> 1) != 0;
        __builtin_amdgcn_s_setprio(1);
        #pragma unroll
        for (int kt = 0; kt < 4; ++kt) {
            int a0 = __shfl((int)u[2 * kt][0], base),      a1 = __shfl((int)u[2 * kt][1], base);
            int a2 = __shfl((int)u[2 * kt][0], base + 16), a3 = __shfl((int)u[2 * kt][1], base + 16);
            int b0 = __shfl((int)u[2 * kt + 1][0], base),      b1 = __shfl((int)u[2 * kt + 1][1], base);
            int b2 = __shfl((int)u[2 * kt + 1][0], base + 16), b3 = __shfl((int)u[2 * kt + 1][1], base + 16);
            union { uint4 u4; short8v s8; } pf;
            pf.u4 = make_uint4((u32)(hiT ? b0 : a0), (u32)(hiT ? b1 : a1),
                               (u32)(hiT ? b2 : a2), (u32)(hiT ? b3 : a3));
            #pragma unroll
            for (int dt = 0; dt < 2; ++dt) {
                short8v vf = *(const short8v*)(smem + VH_OFF + (dt * 16 + cc) * 272 + kt * 64 + qq * 16);
                oacc[dt] = __builtin_amdgcn_mfma_f32_16x16x32_bf16(vf, pf.s8, oacc[dt], 0, 0, 0);
            }
        }
        __builtin_amdgcn_s_setprio(0);
        // O[d=dt*16+4qq+r][i=wv*16+cc] * rden -> OT[i][d]
        #pragma unroll
        for (int dt = 0; dt < 2; ++dt) {
            *(uint2*)(smem + OT_OFF + (wv * 16 + cc) * 80 + (dt * 16 + 4 * qq) * 2) =
                make_uint2(pk2(oacc[dt][0] * rden, oacc[dt][1] * rden),
                           pk2(oacc[dt][2] * rden, oacc[dt][3] * rden));
        }
        __syncthreads();   // B3: OT visible

        // ---- proj accumulate: Y[o][i] += Wp[o][d] * O[i][d] ----
        {
            short8v aw = *(const short8v*)wpb;
            __builtin_amdgcn_s_setprio(1);
            #pragma unroll
            for (int it = 0; it < 8; ++it) {
                short8v of = *(const short8v*)(smem + OT_OFF + (it * 16 + cc) * 80 + qq * 16);
                yacc[it] = __builtin_amdgcn_mfma_f32_16x16x32_bf16(aw, of, yacc[it], 0, 0, 0);
            }
            __builtin_amdgcn_s_setprio(0);
        }
    }

    // ---- epilogue: Y[o = wv*16+4qq+r][l = it*16+cc] ----
    #pragma unroll
    for (int it = 0; it < 8; ++it) {
        #pragma unroll
        for (int r = 0; r < 4; ++r) {
            float y = (yacc[it][r] + biasr[r]) * 0.5f;
            int o = wv * 16 + 4 * qq + r;
            int l = it * 16 + cc;
            size_t idx = ((size_t)(b * 128 + o) * 128 + row) * 128 + l;
            if (pass == 0) out[idx] = y;
            else           g_W2[idx] = f2bf(y);
        }
    }
}

// ---------------- merge: out[b][o][h][w] += T(g_W2[b][o][w][h]) (round-3 proven) ----------------
__global__ __launch_bounds__(256)
void merge_w(float* __restrict__ out)
{
    __shared__ char msm[128 * 264];              // [128 w][264B]
    const int b = blockIdx.x >> 7;
    const int o = blockIdx.x & 127;
    const int tid = threadIdx.x;
    const u16* slab = g_W2 + (size_t)(b * 128 + o) * 16384;
    #pragma unroll
    for (int it = 0; it < 8; ++it) {
        int i = it * 256 + tid;
        int w = i >> 4, h8 = i & 15;
        *(uint4*)(msm + w * 264 + h8 * 16) = *(const uint4*)(slab + w * 128 + h8 * 8);
    }
    __syncthreads();
    float* op = out + (size_t)(b * 128 + o) * 16384;
    #pragma unroll
    for (int it = 0; it < 8; ++it) {
        int i = it * 256 + tid;
        int h = i >> 4, w8 = i & 15;
        float f[8];
        #pragma unroll
        for (int k = 0; k < 8; ++k)
            f[k] = bf2f(*(const u16*)(msm + (w8 * 8 + k) * 264 + h * 2));
        float* dp = op + h * 128 + w8 * 8;
        float4 v0 = *(float4*)dp;
        float4 v1 = *(float4*)(dp + 4);
        v0.x += f[0]; v0.y += f[1]; v0.z += f[2]; v0.w += f[3];
        v1.x += f[4]; v1.y += f[5]; v1.z += f[6]; v1.w += f[7];
        *(float4*)dp = v0;
        *(float4*)(dp + 4) = v1;
    }
}

extern "C" void kernel_launch(void* const* d_in, const int* in_sizes, int n_in,
                              void* d_out, int out_size, void* d_ws, size_t ws_size,
                              hipStream_t stream)
{
    const float* x       = (const float*)d_in[0];
    const float* wqkv_h  = (const float*)d_in[1];
    const float* wproj_h = (const float*)d_in[2];
    const float* bproj_h = (const float*)d_in[3];
    const float* wqkv_w  = (const float*)d_in[4];
    const float* wproj_w = (const float*)d_in[5];
    const float* bproj_w = (const float*)d_in[6];
    float* out = (float*)d_out;

    (void)hipFuncSetAttribute((const void*)attn_kernel,
                              hipFuncAttributeMaxDynamicSharedMemorySize, SMEM_BYTES);

    // 1) pack weights (Q pre-scaled by 1/sqrt(32))
    prep_weights<<<dim3(32), dim3(512), 0, stream>>>(wqkv_h, wproj_h, wqkv_w, wproj_w);
    // 2) x -> bf16 slabs for both passes
    transpose_x<<<dim3(512), dim3(256), 0, stream>>>(x);
    // 3) both attention passes in one dispatch (pass = blockIdx>>10)
    attn_kernel<<<dim3(2048), dim3(512), SMEM_BYTES, stream>>>(bproj_h, bproj_w, out);
    // 4) out += transpose(g_W2)
    merge_w<<<dim3(1024), dim3(256), 0, stream>>>(out);
}